// Round 1
// baseline (1844.649 us; speedup 1.0000x reference)
//
#include <hip/hip_runtime.h>
#include <math.h>

#define B 8
#define N 512
#define NF 32
#define D 128
#define H 4
#define TOK (B*N)   // 4096

__device__ __forceinline__ float lrelu(float x){ return x > 0.f ? x : 0.01f*x; }

// block-wide reductions for blockDim.x == 128 (2 waves)
__device__ __forceinline__ float blocksum128(float v, float* scr){
  #pragma unroll
  for (int m = 32; m; m >>= 1) v += __shfl_xor(v, m, 64);
  __syncthreads();
  if ((threadIdx.x & 63) == 0) scr[threadIdx.x >> 6] = v;
  __syncthreads();
  return scr[0] + scr[1];
}
__device__ __forceinline__ float blockmax128(float v, float* scr){
  #pragma unroll
  for (int m = 32; m; m >>= 1) v = fmaxf(v, __shfl_xor(v, m, 64));
  __syncthreads();
  if ((threadIdx.x & 63) == 0) scr[threadIdx.x >> 6] = v;
  __syncthreads();
  return fmaxf(scr[0], scr[1]);
}

// ---------------- FEL: fused feature-extraction layers, one block per token ----
__global__ void fel_kernel(const float* __restrict__ x,
  const float* __restrict__ w1a, const float* __restrict__ b1a,
  const float* __restrict__ w1b, const float* __restrict__ b1b,
  const float* __restrict__ w2a, const float* __restrict__ b2a,
  const float* __restrict__ w2b, const float* __restrict__ b2b,
  const float* __restrict__ w3a, const float* __restrict__ b3a,
  const float* __restrict__ w3b, const float* __restrict__ b3b,
  float* __restrict__ out)
{
  const int t = blockIdx.x, j = threadIdx.x;
  __shared__ float xs[NF];
  __shared__ float tmp128[D];
  __shared__ float resb[D];
  __shared__ float tmp256[2*D];
  __shared__ float x2b[D];
  __shared__ float scr[2];

  if (j < NF) xs[j] = x[t*NF + j];
  __syncthreads();

  float acc = b1a[j];
  #pragma unroll
  for (int k = 0; k < NF; ++k) acc = fmaf(xs[k], w1a[k*D + j], acc);
  tmp128[j] = lrelu(acc);
  __syncthreads();

  acc = b1b[j];
  #pragma unroll 4
  for (int k = 0; k < D; ++k) acc = fmaf(tmp128[k], w1b[k*D + j], acc);
  float res = lrelu(acc);
  resb[j] = res;
  __syncthreads();

  float a0 = b2a[j], a1 = b2a[j + D];
  #pragma unroll 4
  for (int k = 0; k < D; ++k){ float rv = resb[k];
    a0 = fmaf(rv, w2a[k*2*D + j], a0);
    a1 = fmaf(rv, w2a[k*2*D + j + D], a1); }
  tmp256[j] = lrelu(a0); tmp256[j + D] = lrelu(a1);
  __syncthreads();

  acc = b2b[j];
  #pragma unroll 4
  for (int k = 0; k < 2*D; ++k) acc = fmaf(tmp256[k], w2b[k*D + j], acc);
  float v = lrelu(acc) + res;

  float s  = blocksum128(v, scr);
  float sq = blocksum128(v*v, scr);
  float mean = s * (1.f/D);
  float var  = sq * (1.f/D) - mean*mean;
  float x2 = (v - mean) * rsqrtf(var + 1e-5f);
  x2b[j] = x2;
  __syncthreads();

  a0 = b3a[j]; a1 = b3a[j + D];
  #pragma unroll 4
  for (int k = 0; k < D; ++k){ float xv = x2b[k];
    a0 = fmaf(xv, w3a[k*2*D + j], a0);
    a1 = fmaf(xv, w3a[k*2*D + j + D], a1); }
  tmp256[j] = lrelu(a0); tmp256[j + D] = lrelu(a1);
  __syncthreads();

  acc = b3b[j];
  #pragma unroll 4
  for (int k = 0; k < 2*D; ++k) acc = fmaf(tmp256[k], w3b[k*D + j], acc);
  float v2 = acc + x2;   // NOTE: no lrelu on the outer f3 matmul (matches ref)

  s  = blocksum128(v2, scr);
  sq = blocksum128(v2*v2, scr);
  mean = s * (1.f/D);
  var  = sq * (1.f/D) - mean*mean;
  out[t*D + j] = (v2 - mean) * rsqrtf(var + 1e-5f);
}

// ---------------- Wh = h @ W[head], fused s1/s2 = Wh·a1, Wh·a2 ----------------
// grid = NH*128 blocks (32 tokens per block), block = 128 threads
__global__ void wh_kernel(const float* __restrict__ hin, const float* __restrict__ W,
                          const float* __restrict__ a,
                          float* __restrict__ Wh, float* __restrict__ s1,
                          float* __restrict__ s2)
{
  const int j  = threadIdx.x;
  const int h  = blockIdx.x >> 7;
  const int t0 = (blockIdx.x & 127) * 32;
  __shared__ float xs[32][D];      // 16 KB
  __shared__ float r1[2], r2[2];

  #pragma unroll
  for (int r = 0; r < 32; ++r) xs[r][j] = hin[(t0 + r)*D + j];
  __syncthreads();

  const float* w = W + (size_t)h*D*D;
  float acc[32];
  #pragma unroll
  for (int r = 0; r < 32; ++r) acc[r] = 0.f;
  for (int k = 0; k < D; ++k){
    float wkj = w[k*D + j];
    #pragma unroll
    for (int r = 0; r < 32; ++r) acc[r] = fmaf(xs[r][k], wkj, acc[r]);
  }

  const float a1j = a[h*2*D + j], a2j = a[h*2*D + D + j];
  for (int r = 0; r < 32; ++r){
    Wh[((size_t)h*TOK + t0 + r)*D + j] = acc[r];
    float p1 = acc[r]*a1j, p2 = acc[r]*a2j;
    #pragma unroll
    for (int m = 32; m; m >>= 1){ p1 += __shfl_xor(p1, m, 64); p2 += __shfl_xor(p2, m, 64); }
    __syncthreads();
    if ((j & 63) == 0){ r1[j>>6] = p1; r2[j>>6] = p2; }
    __syncthreads();
    if (j == 0){ s1[h*TOK + t0 + r] = r1[0] + r1[1]; s2[h*TOK + t0 + r] = r2[0] + r2[1]; }
  }
}

// ---------------- masked softmax attention row + att@Wh -----------------------
// MODE 0: elu epilogue (inner blocks). MODE 1: lrelu epilogue (output GAT).
// TRANS 0: mask = adj[b,i,j] > 0. TRANS 1: mask = adj[b,j,i] > 0.
template<int MODE, int TRANS>
__global__ void attn_kernel(const float* __restrict__ Wh, const float* __restrict__ s1,
                            const float* __restrict__ s2, const int* __restrict__ adj,
                            float* __restrict__ out)
{
  const int j = threadIdx.x;
  const int h = blockIdx.x >> 12;
  const int t = blockIdx.x & (TOK-1);
  const int b = t >> 9, i = t & (N-1);
  __shared__ float s2r[N];
  __shared__ float att[N];
  __shared__ float scr[2];

  const int hb = h*TOK + b*N;
  const float s1i = s1[h*TOK + t];
  #pragma unroll
  for (int q = 0; q < 4; ++q) s2r[q*D + j] = s2[hb + q*D + j];
  __syncthreads();

  bool mk[4]; float e[4]; float mx = -3.0e38f;
  #pragma unroll
  for (int q = 0; q < 4; ++q){
    int jj = q*D + j;
    int av = TRANS ? adj[((size_t)(b*N) + jj)*N + i] : adj[((size_t)(b*N) + i)*N + jj];
    mk[q] = av > 0;
    float ee = lrelu(s1i * s2r[jj]);
    ee = mk[q] ? ee : -9.0e15f;
    e[q] = ee;
    mx = fmaxf(mx, ee);
  }
  mx = blockmax128(mx, scr);
  float sum = 0.f;
  #pragma unroll
  for (int q = 0; q < 4; ++q){
    float ex = mk[q] ? expf(e[q] - mx) : 0.f;
    e[q] = ex; sum += ex;
  }
  sum = blocksum128(sum, scr);
  float inv = sum > 0.f ? 1.f/sum : 0.f;   // all-masked row -> zeros (matches ref)
  #pragma unroll
  for (int q = 0; q < 4; ++q) att[q*D + j] = e[q]*inv;
  __syncthreads();

  const float* whb = Wh + (size_t)hb*D;
  float acc = 0.f;
  #pragma unroll 8
  for (int k = 0; k < N; ++k) acc = fmaf(att[k], whb[(size_t)k*D + j], acc);

  if (MODE == 0) acc = acc > 0.f ? acc : expm1f(acc);   // elu
  else           acc = lrelu(acc);
  out[((size_t)h*TOK + t)*D + j] = acc;
}

// ---------------- head-concat @ resh_W + bias + residual + layernorm ----------
__global__ void resh_kernel(const float* __restrict__ hp, const float* __restrict__ rW,
                            const float* __restrict__ rb, const float* __restrict__ res,
                            float* __restrict__ out)
{
  const int t = blockIdx.x, j = threadIdx.x;
  __shared__ float v[H*D];
  __shared__ float scr[2];
  #pragma unroll
  for (int q = 0; q < H; ++q) v[q*D + j] = hp[((size_t)q*TOK + t)*D + j];
  __syncthreads();
  float acc = rb[j];
  #pragma unroll 4
  for (int c = 0; c < H*D; ++c) acc = fmaf(v[c], rW[c*D + j], acc);
  acc += res[t*D + j];
  float s  = blocksum128(acc, scr);
  float sq = blocksum128(acc*acc, scr);
  float mean = s*(1.f/D), var = sq*(1.f/D) - mean*mean;
  out[t*D + j] = (acc - mean)*rsqrtf(var + 1e-5f);
}

// ---------------- mean over n + projection -----------------------------------
__global__ void final_kernel(const float* __restrict__ hF, const float* __restrict__ hT,
                             const float* __restrict__ pW, const float* __restrict__ pb,
                             float* __restrict__ out)
{
  const int b = blockIdx.x, c = threadIdx.x;
  __shared__ float scr[4];
  const float* src = (c < D) ? (hF + (size_t)b*N*D + c) : (hT + (size_t)b*N*D + (c - D));
  float s = 0.f;
  for (int n = 0; n < N; ++n) s += src[(size_t)n*D];
  s *= (1.f/N);
  float p = s * pW[c];
  #pragma unroll
  for (int m = 32; m; m >>= 1) p += __shfl_xor(p, m, 64);
  __syncthreads();
  if ((c & 63) == 0) scr[c >> 6] = p;
  __syncthreads();
  if (c == 0) out[b] = scr[0] + scr[1] + scr[2] + scr[3] + pb[0];
}

extern "C" void kernel_launch(void* const* d_in, const int* in_sizes, int n_in,
                              void* d_out, int out_size, void* d_ws, size_t ws_size,
                              hipStream_t stream)
{
  (void)in_sizes; (void)n_in; (void)out_size; (void)ws_size;
  const float* x    = (const float*)d_in[0];
  const int*   adj  = (const int*)d_in[1];
  // d_in[2] = layer_id (unused by reference)
  const float* f1w1 = (const float*)d_in[3];
  const float* f1b1 = (const float*)d_in[4];
  const float* f1w2 = (const float*)d_in[5];
  const float* f1b2 = (const float*)d_in[6];
  const float* f2w1 = (const float*)d_in[7];
  const float* f2b1 = (const float*)d_in[8];
  const float* f2w2 = (const float*)d_in[9];
  const float* f2b2 = (const float*)d_in[10];
  const float* f3w1 = (const float*)d_in[11];
  const float* f3b1 = (const float*)d_in[12];
  const float* f3w2 = (const float*)d_in[13];
  const float* f3b2 = (const float*)d_in[14];
  const float* attW = (const float*)d_in[15];
  const float* attA = (const float*)d_in[16];
  const float* rshW = (const float*)d_in[17];
  const float* rshB = (const float*)d_in[18];
  const float* outW = (const float*)d_in[19];
  const float* outA = (const float*)d_in[20];
  const float* pW   = (const float*)d_in[21];
  const float* pb   = (const float*)d_in[22];

  float* p  = (float*)d_ws;
  float* hA = p; p += TOK*D;
  float* hB = p; p += TOK*D;
  float* hF = p; p += TOK*D;
  float* Wh = p; p += H*TOK*D;
  float* hp = p; p += H*TOK*D;
  float* s1 = p; p += H*TOK;
  float* s2 = p; p += H*TOK;

  // FEL
  fel_kernel<<<TOK, D, 0, stream>>>(x, f1w1,f1b1,f1w2,f1b2, f2w1,f2b1,f2w2,f2b2,
                                    f3w1,f3b1,f3w2,f3b2, hA);

  // forward attention blocks 0..2
  float* cur = hA; float* nxt = hB;
  for (int i = 0; i < 3; ++i){
    wh_kernel<<<H*128, D, 0, stream>>>(cur, attW + (size_t)i*H*D*D,
                                       attA + (size_t)i*H*2*D, Wh, s1, s2);
    attn_kernel<0,0><<<H*TOK, D, 0, stream>>>(Wh, s1, s2, adj, hp);
    resh_kernel<<<TOK, D, 0, stream>>>(hp, rshW + (size_t)i*H*D*D,
                                       rshB + (size_t)i*D, cur, nxt);
    float* t_ = cur; cur = nxt; nxt = t_;
  }
  // forward output GAT (single head, lrelu) -> hF
  wh_kernel<<<128, D, 0, stream>>>(cur, outW, outA, Wh, s1, s2);
  attn_kernel<1,0><<<TOK, D, 0, stream>>>(Wh, s1, s2, adj, hF);

  // transposed attention blocks 3..5 (start from hF, never overwrite hF)
  cur = hF; nxt = hA;
  for (int i = 3; i < 6; ++i){
    wh_kernel<<<H*128, D, 0, stream>>>(cur, attW + (size_t)i*H*D*D,
                                       attA + (size_t)i*H*2*D, Wh, s1, s2);
    attn_kernel<0,1><<<H*TOK, D, 0, stream>>>(Wh, s1, s2, adj, hp);
    resh_kernel<<<TOK, D, 0, stream>>>(hp, rshW + (size_t)i*H*D*D,
                                       rshB + (size_t)i*D, cur, nxt);
    cur = nxt; nxt = (cur == hA) ? hB : hA;
  }
  // transposed output GAT -> nxt (hA or hB, distinct from hF)
  wh_kernel<<<128, D, 0, stream>>>(cur, outW + D*D, outA + 2*D, Wh, s1, s2);
  attn_kernel<1,1><<<TOK, D, 0, stream>>>(Wh, s1, s2, adj, nxt);

  // mean + projection
  final_kernel<<<B, 2*D, 0, stream>>>(hF, nxt, pW, pb, (float*)d_out);
}

// Round 2
// 986.529 us; speedup vs baseline: 1.8698x; 1.8698x over previous
//
#include <hip/hip_runtime.h>
#include <math.h>

#define B 8
#define N 512
#define NF 32
#define D 128
#define H 4
#define TOK (B*N)   // 4096

__device__ __forceinline__ float lrelu(float x){ return x > 0.f ? x : 0.01f*x; }

// ---------------- adj transpose (per batch) -----------------------------------
__global__ void transpose_kernel(const int* __restrict__ adj, int* __restrict__ adjT){
  __shared__ int tile[32][33];
  const int b = blockIdx.z;
  const int i0 = blockIdx.y*32, j0 = blockIdx.x*32;
  const int tx = threadIdx.x & 31, ty = threadIdx.x >> 5;  // 32 x 8
  for (int r = ty; r < 32; r += 8)
    tile[r][tx] = adj[((size_t)b*N + i0 + r)*N + j0 + tx];
  __syncthreads();
  for (int r = ty; r < 32; r += 8)
    adjT[((size_t)b*N + j0 + r)*N + i0 + tx] = tile[tx][r];
}

// ---------------- FEL: fused feature-extraction, one block per token ----------
__global__ void fel_kernel(const float* __restrict__ x,
  const float* __restrict__ w1a, const float* __restrict__ b1a,
  const float* __restrict__ w1b, const float* __restrict__ b1b,
  const float* __restrict__ w2a, const float* __restrict__ b2a,
  const float* __restrict__ w2b, const float* __restrict__ b2b,
  const float* __restrict__ w3a, const float* __restrict__ b3a,
  const float* __restrict__ w3b, const float* __restrict__ b3b,
  float* __restrict__ out)
{
  const int t = blockIdx.x, j = threadIdx.x;
  __shared__ float xs[NF];
  __shared__ float tmp128[D];
  __shared__ float resb[D];
  __shared__ float tmp256[2*D];
  __shared__ float x2b[D];
  __shared__ float scr[2];

  if (j < NF) xs[j] = x[t*NF + j];
  __syncthreads();

  float acc = b1a[j];
  #pragma unroll
  for (int k = 0; k < NF; ++k) acc = fmaf(xs[k], w1a[k*D + j], acc);
  tmp128[j] = lrelu(acc);
  __syncthreads();

  acc = b1b[j];
  #pragma unroll 4
  for (int k = 0; k < D; ++k) acc = fmaf(tmp128[k], w1b[k*D + j], acc);
  float res = lrelu(acc);
  resb[j] = res;
  __syncthreads();

  float a0 = b2a[j], a1 = b2a[j + D];
  #pragma unroll 4
  for (int k = 0; k < D; ++k){ float rv = resb[k];
    a0 = fmaf(rv, w2a[k*2*D + j], a0);
    a1 = fmaf(rv, w2a[k*2*D + j + D], a1); }
  tmp256[j] = lrelu(a0); tmp256[j + D] = lrelu(a1);
  __syncthreads();

  acc = b2b[j];
  #pragma unroll 4
  for (int k = 0; k < 2*D; ++k) acc = fmaf(tmp256[k], w2b[k*D + j], acc);
  float v = lrelu(acc) + res;

  // blocksum over 128 threads
  float s = v, sq = v*v;
  #pragma unroll
  for (int m = 32; m; m >>= 1){ s += __shfl_xor(s, m, 64); sq += __shfl_xor(sq, m, 64); }
  __syncthreads();
  if ((j & 63) == 0){ scr[j>>6] = s; }
  __syncthreads();
  float s01 = scr[0] + scr[1];
  __syncthreads();
  if ((j & 63) == 0){ scr[j>>6] = sq; }
  __syncthreads();
  float sq01 = scr[0] + scr[1];
  float mean = s01 * (1.f/D);
  float var  = sq01 * (1.f/D) - mean*mean;
  float x2 = (v - mean) * rsqrtf(var + 1e-5f);
  x2b[j] = x2;
  __syncthreads();

  a0 = b3a[j]; a1 = b3a[j + D];
  #pragma unroll 4
  for (int k = 0; k < D; ++k){ float xv = x2b[k];
    a0 = fmaf(xv, w3a[k*2*D + j], a0);
    a1 = fmaf(xv, w3a[k*2*D + j + D], a1); }
  tmp256[j] = lrelu(a0); tmp256[j + D] = lrelu(a1);
  __syncthreads();

  acc = b3b[j];
  #pragma unroll 4
  for (int k = 0; k < 2*D; ++k) acc = fmaf(tmp256[k], w3b[k*D + j], acc);
  float v2 = acc + x2;   // no lrelu on outer f3 matmul (matches ref)

  s = v2; sq = v2*v2;
  #pragma unroll
  for (int m = 32; m; m >>= 1){ s += __shfl_xor(s, m, 64); sq += __shfl_xor(sq, m, 64); }
  __syncthreads();
  if ((j & 63) == 0){ scr[j>>6] = s; }
  __syncthreads();
  s01 = scr[0] + scr[1];
  __syncthreads();
  if ((j & 63) == 0){ scr[j>>6] = sq; }
  __syncthreads();
  sq01 = scr[0] + scr[1];
  mean = s01 * (1.f/D);
  var  = sq01 * (1.f/D) - mean*mean;
  out[t*D + j] = (v2 - mean) * rsqrtf(var + 1e-5f);
}

// ---------------- shared GEMM micro-kernel pieces -----------------------------
// Block: 256 threads. C-tile 64 rows x 128 cols. Micro-tile: 4 rows x 8 cols
// (cols c0a..c0a+3 and c0a+64..c0a+67). K staged in chunks of 32.
// As[64][36] (pad stride 36 keeps float4 alignment + conflict-free banks).
__device__ __forceinline__ void gemm_chunk(const float (*As)[36], const float (*Ws)[128],
                                           int r0, int c0a, float acc[4][8]){
  #pragma unroll
  for (int kk4 = 0; kk4 < 8; ++kk4){
    float4 av[4];
    #pragma unroll
    for (int i = 0; i < 4; ++i) av[i] = *(const float4*)&As[r0+i][kk4*4];
    #pragma unroll
    for (int u = 0; u < 4; ++u){
      float4 w0 = *(const float4*)&Ws[kk4*4+u][c0a];
      float4 w1 = *(const float4*)&Ws[kk4*4+u][c0a+64];
      float wv[8] = {w0.x,w0.y,w0.z,w0.w,w1.x,w1.y,w1.z,w1.w};
      #pragma unroll
      for (int i = 0; i < 4; ++i){
        float a = (u==0)?av[i].x:(u==1)?av[i].y:(u==2)?av[i].z:av[i].w;
        #pragma unroll
        for (int c = 0; c < 8; ++c) acc[i][c] = fmaf(a, wv[c], acc[i][c]);
      }
    }
  }
}

// ---------------- Wh = h @ W[head] + fused s1/s2 ------------------------------
// grid = HH*64, block 256
__global__ void wh_gemm(const float* __restrict__ hin, const float* __restrict__ W,
                        const float* __restrict__ a,
                        float* __restrict__ Wh, float* __restrict__ s1,
                        float* __restrict__ s2)
{
  const int tid = threadIdx.x;
  const int h  = blockIdx.x >> 6;
  const int t0 = (blockIdx.x & 63) * 64;
  __shared__ float As[64][36];
  __shared__ float Ws[32][128];
  const float* Ab = hin + (size_t)t0*D;
  const float* Wb = W + (size_t)h*D*D;
  const int lr = tid >> 2, lq = tid & 3;
  const int wk = tid >> 3, wsg = tid & 7;
  const int r0 = (tid >> 4)*4, c0a = (tid & 15)*4;
  float acc[4][8];
  #pragma unroll
  for (int i=0;i<4;++i){
    #pragma unroll
    for (int c=0;c<8;++c) acc[i][c]=0.f; }

  for (int k0 = 0; k0 < D; k0 += 32){
    const float* ap = Ab + (size_t)lr*D + k0 + lq*8;
    float4 a0 = *(const float4*)ap, a1 = *(const float4*)(ap+4);
    *(float4*)&As[lr][lq*8]   = a0;
    *(float4*)&As[lr][lq*8+4] = a1;
    const float* wp = Wb + (size_t)(k0+wk)*D + wsg*16;
    float4 w0=*(const float4*)wp, w1=*(const float4*)(wp+4),
           w2=*(const float4*)(wp+8), w3=*(const float4*)(wp+12);
    *(float4*)&Ws[wk][wsg*16]    = w0;
    *(float4*)&Ws[wk][wsg*16+4]  = w1;
    *(float4*)&Ws[wk][wsg*16+8]  = w2;
    *(float4*)&Ws[wk][wsg*16+12] = w3;
    __syncthreads();
    gemm_chunk(As, Ws, r0, c0a, acc);
    __syncthreads();
  }

  const float* aa = a + (size_t)h*2*D;
  float a1v[8], a2v[8];
  #pragma unroll
  for (int c=0;c<8;++c){
    int col = (c<4) ? (c0a+c) : (c0a+60+c);
    a1v[c] = aa[col]; a2v[c] = aa[D+col];
  }
  float* ob = Wh + ((size_t)h*TOK + t0)*D;
  #pragma unroll
  for (int i=0;i<4;++i){
    float4 o0 = {acc[i][0],acc[i][1],acc[i][2],acc[i][3]};
    float4 o1 = {acc[i][4],acc[i][5],acc[i][6],acc[i][7]};
    *(float4*)(ob + (size_t)(r0+i)*D + c0a)      = o0;
    *(float4*)(ob + (size_t)(r0+i)*D + c0a + 64) = o1;
    float p1 = 0.f, p2 = 0.f;
    #pragma unroll
    for (int c=0;c<8;++c){ p1 = fmaf(acc[i][c], a1v[c], p1); p2 = fmaf(acc[i][c], a2v[c], p2); }
    #pragma unroll
    for (int m=1; m<16; m<<=1){ p1 += __shfl_xor(p1, m, 64); p2 += __shfl_xor(p2, m, 64); }
    if ((tid & 15) == 0){
      s1[(size_t)h*TOK + t0 + r0 + i] = p1;
      s2[(size_t)h*TOK + t0 + r0 + i] = p2;
    }
  }
}

// ---------------- fused score+softmax+PV GEMM ---------------------------------
// MODE 0: elu epilogue, MODE 1: lrelu. mask ptr = adj or adjT (per batch layout).
// grid = HH*64, block 256
template<int MODE>
__global__ void pv_gemm(const float* __restrict__ s1, const float* __restrict__ s2,
                        const int* __restrict__ mask, const float* __restrict__ Wh,
                        float* __restrict__ out)
{
  const int tid = threadIdx.x;
  const int h  = blockIdx.x >> 6;
  const int t0 = (blockIdx.x & 63) * 64;
  const int b  = t0 >> 9;
  const int i0 = t0 & (N-1);
  __shared__ float s2s[N];
  __shared__ float s1s[64];
  __shared__ float mxs[64];
  __shared__ float invs[64];
  __shared__ float As[64][36];
  __shared__ float Ws[32][128];

  s2s[tid]     = s2[(size_t)h*TOK + b*N + tid];
  s2s[tid+256] = s2[(size_t)h*TOK + b*N + tid + 256];
  if (tid < 64) s1s[tid] = s1[(size_t)h*TOK + b*N + i0 + tid];
  __syncthreads();

  // ---- per-row softmax stats: 4 threads per row, 128 cols each ----
  {
    const int row = tid >> 2, q = tid & 3;
    const float s1v = s1s[row];
    const int* mrow = mask + ((size_t)b*N + i0 + row)*N + q*128;
    float mx = -3.4e38f;
    const int4* mp = (const int4*)mrow;
    #pragma unroll 8
    for (int it = 0; it < 32; ++it){
      int4 m4 = mp[it];
      int jb = q*128 + it*4;
      float e0 = lrelu(s1v*s2s[jb+0]), e1 = lrelu(s1v*s2s[jb+1]);
      float e2 = lrelu(s1v*s2s[jb+2]), e3 = lrelu(s1v*s2s[jb+3]);
      mx = fmaxf(mx, m4.x>0 ? e0 : -3.4e38f);
      mx = fmaxf(mx, m4.y>0 ? e1 : -3.4e38f);
      mx = fmaxf(mx, m4.z>0 ? e2 : -3.4e38f);
      mx = fmaxf(mx, m4.w>0 ? e3 : -3.4e38f);
    }
    #pragma unroll
    for (int m=1; m<4; m<<=1) mx = fmaxf(mx, __shfl_xor(mx, m, 64));
    float sum = 0.f;
    #pragma unroll 8
    for (int it = 0; it < 32; ++it){
      int4 m4 = mp[it];
      int jb = q*128 + it*4;
      float e0 = lrelu(s1v*s2s[jb+0]), e1 = lrelu(s1v*s2s[jb+1]);
      float e2 = lrelu(s1v*s2s[jb+2]), e3 = lrelu(s1v*s2s[jb+3]);
      sum += m4.x>0 ? __expf(e0-mx) : 0.f;
      sum += m4.y>0 ? __expf(e1-mx) : 0.f;
      sum += m4.z>0 ? __expf(e2-mx) : 0.f;
      sum += m4.w>0 ? __expf(e3-mx) : 0.f;
    }
    #pragma unroll
    for (int m=1; m<4; m<<=1) sum += __shfl_xor(sum, m, 64);
    if (q == 0){ mxs[row] = mx; invs[row] = (sum > 0.f) ? 1.f/sum : 0.f; }
  }
  __syncthreads();

  // ---- PV GEMM with att tile regenerated per K-chunk ----
  const float* Wb = Wh + ((size_t)h*TOK + (size_t)b*N)*D;
  const int lr = tid >> 2, lq = tid & 3;
  const int wk = tid >> 3, wsg = tid & 7;
  const int r0 = (tid >> 4)*4, c0a = (tid & 15)*4;
  const float s1lr = s1s[lr];
  const float mxlr = mxs[lr], invlr = invs[lr];
  const int* mrow2 = mask + ((size_t)b*N + i0 + lr)*N;
  float acc[4][8];
  #pragma unroll
  for (int i=0;i<4;++i){
    #pragma unroll
    for (int c=0;c<8;++c) acc[i][c]=0.f; }

  for (int k0 = 0; k0 < N; k0 += 32){
    // stage att chunk: thread computes 8 values of row lr
    {
      const int4* mp = (const int4*)(mrow2 + k0 + lq*8);
      int4 m0 = mp[0], m1 = mp[1];
      int jb = k0 + lq*8;
      float v[8];
      int mm[8] = {m0.x,m0.y,m0.z,m0.w,m1.x,m1.y,m1.z,m1.w};
      #pragma unroll
      for (int w2=0; w2<8; ++w2){
        float e = lrelu(s1lr * s2s[jb+w2]);
        v[w2] = (mm[w2] > 0) ? __expf(e - mxlr)*invlr : 0.f;
      }
      float4 v0 = {v[0],v[1],v[2],v[3]}, v1 = {v[4],v[5],v[6],v[7]};
      *(float4*)&As[lr][lq*8]   = v0;
      *(float4*)&As[lr][lq*8+4] = v1;
    }
    const float* wp = Wb + (size_t)(k0+wk)*D + wsg*16;
    float4 w0=*(const float4*)wp, w1=*(const float4*)(wp+4),
           w2=*(const float4*)(wp+8), w3=*(const float4*)(wp+12);
    *(float4*)&Ws[wk][wsg*16]    = w0;
    *(float4*)&Ws[wk][wsg*16+4]  = w1;
    *(float4*)&Ws[wk][wsg*16+8]  = w2;
    *(float4*)&Ws[wk][wsg*16+12] = w3;
    __syncthreads();
    gemm_chunk(As, Ws, r0, c0a, acc);
    __syncthreads();
  }

  float* ob = out + ((size_t)h*TOK + t0)*D;
  #pragma unroll
  for (int i=0;i<4;++i){
    float v[8];
    #pragma unroll
    for (int c=0;c<8;++c){
      float xv = acc[i][c];
      v[c] = (MODE==0) ? (xv > 0.f ? xv : expm1f(xv)) : lrelu(xv);
    }
    float4 o0 = {v[0],v[1],v[2],v[3]}, o1 = {v[4],v[5],v[6],v[7]};
    *(float4*)(ob + (size_t)(r0+i)*D + c0a)      = o0;
    *(float4*)(ob + (size_t)(r0+i)*D + c0a + 64) = o1;
  }
}

// ---------------- concat-heads @ resh_W + bias + residual + LN ----------------
// grid = 64, block 256
__global__ void resh_gemm(const float* __restrict__ hp, const float* __restrict__ rW,
                          const float* __restrict__ rb, const float* __restrict__ res,
                          float* __restrict__ out)
{
  const int tid = threadIdx.x;
  const int t0 = blockIdx.x * 64;
  __shared__ float As[64][36];
  __shared__ float Ws[32][128];
  const int lr = tid >> 2, lq = tid & 3;
  const int wk = tid >> 3, wsg = tid & 7;
  const int r0 = (tid >> 4)*4, c0a = (tid & 15)*4;
  float acc[4][8];
  #pragma unroll
  for (int i=0;i<4;++i){
    #pragma unroll
    for (int c=0;c<8;++c) acc[i][c]=0.f; }

  for (int k0 = 0; k0 < H*D; k0 += 32){
    // A[t][k], k = h*128 + kk  ->  hp[(k>>7)*TOK + t][k&127]
    const float* Ab = hp + ((size_t)(k0 >> 7)*TOK + t0)*D + (k0 & (D-1));
    const float* ap = Ab + (size_t)lr*D + lq*8;
    float4 a0 = *(const float4*)ap, a1 = *(const float4*)(ap+4);
    *(float4*)&As[lr][lq*8]   = a0;
    *(float4*)&As[lr][lq*8+4] = a1;
    const float* wp = rW + (size_t)(k0+wk)*D + wsg*16;
    float4 w0=*(const float4*)wp, w1=*(const float4*)(wp+4),
           w2=*(const float4*)(wp+8), w3=*(const float4*)(wp+12);
    *(float4*)&Ws[wk][wsg*16]    = w0;
    *(float4*)&Ws[wk][wsg*16+4]  = w1;
    *(float4*)&Ws[wk][wsg*16+8]  = w2;
    *(float4*)&Ws[wk][wsg*16+12] = w3;
    __syncthreads();
    gemm_chunk(As, Ws, r0, c0a, acc);
    __syncthreads();
  }

  float rbv[8];
  #pragma unroll
  for (int c=0;c<8;++c) rbv[c] = rb[(c<4)?(c0a+c):(c0a+60+c)];
  #pragma unroll
  for (int i=0;i<4;++i){
    const float* rr = res + (size_t)(t0+r0+i)*D;
    float4 q0 = *(const float4*)(rr + c0a);
    float4 q1 = *(const float4*)(rr + c0a + 64);
    float rv[8] = {q0.x,q0.y,q0.z,q0.w,q1.x,q1.y,q1.z,q1.w};
    float v[8]; float s=0.f, sq=0.f;
    #pragma unroll
    for (int c=0;c<8;++c){
      float xv = acc[i][c] + rbv[c] + rv[c];
      v[c] = xv; s += xv; sq += xv*xv;
    }
    #pragma unroll
    for (int m=1; m<16; m<<=1){ s += __shfl_xor(s, m, 64); sq += __shfl_xor(sq, m, 64); }
    float mean = s*(1.f/D);
    float var  = sq*(1.f/D) - mean*mean;
    float rstd = rsqrtf(var + 1e-5f);
    float o[8];
    #pragma unroll
    for (int c=0;c<8;++c) o[c] = (v[c]-mean)*rstd;
    float* ob = out + (size_t)(t0+r0+i)*D;
    float4 o0 = {o[0],o[1],o[2],o[3]}, o1 = {o[4],o[5],o[6],o[7]};
    *(float4*)(ob + c0a)      = o0;
    *(float4*)(ob + c0a + 64) = o1;
  }
}

// ---------------- mean over n + projection -----------------------------------
__global__ void final_kernel(const float* __restrict__ hF, const float* __restrict__ hT,
                             const float* __restrict__ pW, const float* __restrict__ pb,
                             float* __restrict__ out)
{
  const int b = blockIdx.x, c = threadIdx.x;
  __shared__ float scr[4];
  const float* src = (c < D) ? (hF + (size_t)b*N*D + c) : (hT + (size_t)b*N*D + (c - D));
  float s = 0.f;
  for (int n = 0; n < N; ++n) s += src[(size_t)n*D];
  s *= (1.f/N);
  float p = s * pW[c];
  #pragma unroll
  for (int m = 32; m; m >>= 1) p += __shfl_xor(p, m, 64);
  __syncthreads();
  if ((c & 63) == 0) scr[c >> 6] = p;
  __syncthreads();
  if (c == 0) out[b] = scr[0] + scr[1] + scr[2] + scr[3] + pb[0];
}

extern "C" void kernel_launch(void* const* d_in, const int* in_sizes, int n_in,
                              void* d_out, int out_size, void* d_ws, size_t ws_size,
                              hipStream_t stream)
{
  (void)in_sizes; (void)n_in; (void)out_size; (void)ws_size;
  const float* x    = (const float*)d_in[0];
  const int*   adj  = (const int*)d_in[1];
  const float* f1w1 = (const float*)d_in[3];
  const float* f1b1 = (const float*)d_in[4];
  const float* f1w2 = (const float*)d_in[5];
  const float* f1b2 = (const float*)d_in[6];
  const float* f2w1 = (const float*)d_in[7];
  const float* f2b1 = (const float*)d_in[8];
  const float* f2w2 = (const float*)d_in[9];
  const float* f2b2 = (const float*)d_in[10];
  const float* f3w1 = (const float*)d_in[11];
  const float* f3b1 = (const float*)d_in[12];
  const float* f3w2 = (const float*)d_in[13];
  const float* f3b2 = (const float*)d_in[14];
  const float* attW = (const float*)d_in[15];
  const float* attA = (const float*)d_in[16];
  const float* rshW = (const float*)d_in[17];
  const float* rshB = (const float*)d_in[18];
  const float* outW = (const float*)d_in[19];
  const float* outA = (const float*)d_in[20];
  const float* pW   = (const float*)d_in[21];
  const float* pb   = (const float*)d_in[22];

  float* p  = (float*)d_ws;
  float* hA = p; p += (size_t)TOK*D;
  float* hB = p; p += (size_t)TOK*D;
  float* hF = p; p += (size_t)TOK*D;
  float* Wh = p; p += (size_t)H*TOK*D;
  float* hp = p; p += (size_t)H*TOK*D;
  float* s1 = p; p += (size_t)H*TOK;
  float* s2 = p; p += (size_t)H*TOK;
  int* adjT = (int*)p;

  transpose_kernel<<<dim3(16,16,8), 256, 0, stream>>>(adj, adjT);
  fel_kernel<<<TOK, D, 0, stream>>>(x, f1w1,f1b1,f1w2,f1b2, f2w1,f2b1,f2w2,f2b2,
                                    f3w1,f3b1,f3w2,f3b2, hA);

  // forward attention blocks 0..2
  float* cur = hA; float* nxt = hB;
  for (int i = 0; i < 3; ++i){
    wh_gemm<<<H*64, 256, 0, stream>>>(cur, attW + (size_t)i*H*D*D,
                                      attA + (size_t)i*H*2*D, Wh, s1, s2);
    pv_gemm<0><<<H*64, 256, 0, stream>>>(s1, s2, adj, Wh, hp);
    resh_gemm<<<64, 256, 0, stream>>>(hp, rshW + (size_t)i*H*D*D,
                                      rshB + (size_t)i*D, cur, nxt);
    float* t_ = cur; cur = nxt; nxt = t_;
  }
  // forward output GAT (single head, lrelu) -> hF
  wh_gemm<<<64, 256, 0, stream>>>(cur, outW, outA, Wh, s1, s2);
  pv_gemm<1><<<64, 256, 0, stream>>>(s1, s2, adj, Wh, hF);

  // transposed attention blocks 3..5
  cur = hF; nxt = hA;
  for (int i = 3; i < 6; ++i){
    wh_gemm<<<H*64, 256, 0, stream>>>(cur, attW + (size_t)i*H*D*D,
                                      attA + (size_t)i*H*2*D, Wh, s1, s2);
    pv_gemm<0><<<H*64, 256, 0, stream>>>(s1, s2, adjT, Wh, hp);
    resh_gemm<<<64, 256, 0, stream>>>(hp, rshW + (size_t)i*H*D*D,
                                      rshB + (size_t)i*D, cur, nxt);
    cur = nxt; nxt = (cur == hA) ? hB : hA;
  }
  // transposed output GAT -> hT (= nxt, distinct from hF)
  wh_gemm<<<64, 256, 0, stream>>>(cur, outW + D*D, outA + 2*D, Wh, s1, s2);
  pv_gemm<1><<<64, 256, 0, stream>>>(s1, s2, adjT, Wh, nxt);

  final_kernel<<<B, 2*D, 0, stream>>>(hF, nxt, pW, pb, (float*)d_out);
}

// Round 3
// 540.060 us; speedup vs baseline: 3.4156x; 1.8267x over previous
//
#include <hip/hip_runtime.h>
#include <math.h>

#define B 8
#define N 512
#define D 128
#define H 4
#define TOK (B*N)   // 4096

typedef __attribute__((ext_vector_type(8))) short bfrag;   // 8 bf16 (4 VGPRs)
typedef __attribute__((ext_vector_type(4))) float facc;    // 4 fp32 acc
typedef unsigned short u16;
typedef unsigned int u32;

__device__ __forceinline__ float lrelu(float x){ return x > 0.f ? x : 0.01f*x; }
__device__ __forceinline__ u16 f2bf(float f){
  u32 u = __float_as_uint(f);
  u += 0x7fffu + ((u >> 16) & 1u);     // RTNE
  return (u16)(u >> 16);
}
__device__ __forceinline__ u32 pk2(float a, float b){
  return (u32)f2bf(a) | ((u32)f2bf(b) << 16);
}

// ---------------- adj transpose (per batch) -----------------------------------
__global__ void transpose_kernel(const int* __restrict__ adj, int* __restrict__ adjT){
  __shared__ int tile[32][33];
  const int b = blockIdx.z;
  const int i0 = blockIdx.y*32, j0 = blockIdx.x*32;
  const int tx = threadIdx.x & 31, ty = threadIdx.x >> 5;
  for (int r = ty; r < 32; r += 8)
    tile[r][tx] = adj[((size_t)b*N + i0 + r)*N + j0 + tx];
  __syncthreads();
  for (int r = ty; r < 32; r += 8)
    adjT[((size_t)b*N + j0 + r)*N + i0 + tx] = tile[tx][r];
}

// ---------------- weight transpose + bf16 cast: dst[n][k] = bf16(src[k][n]) ---
// grid (N/32, K/32, count), block 256
__global__ void wtrans(const float* __restrict__ src, u16* __restrict__ dst,
                       int K, int Nn){
  const int z = blockIdx.z;
  src += (size_t)z*K*Nn; dst += (size_t)z*K*Nn;
  __shared__ float tile[32][33];
  const int n0 = blockIdx.x*32, k0 = blockIdx.y*32;
  const int tx = threadIdx.x & 31, ty = threadIdx.x >> 5;
  for (int r = ty; r < 32; r += 8)
    tile[r][tx] = src[(size_t)(k0+r)*Nn + n0 + tx];
  __syncthreads();
  for (int r = ty; r < 32; r += 8)
    dst[(size_t)(n0+r)*K + k0 + tx] = f2bf(tile[tx][r]);
}

// =====================  MFMA GEMM tile core (shared pattern)  =================
// Block 256 = 4 waves. C-tile 64 rows x 128 cols; wave w owns rows 16w..16w+15.
// A staged bf16 As[64][40] (pad 40 -> even bank-granule spread), B staged bf16
// Bs[128][40] in BT[n][k] order so every frag read is a contiguous ds_read_b128.
// Frag layouts (HW-verified per guide): A[m=lane&15][k=quad*8+j],
// B[k=quad*8+j][n=lane&15], C: col=lane&15, row=quad*4+reg.

// ---------------- generic GEMM + epilogue (FEL stages + resh) -----------------
// ACT: 0 none, 1 lrelu(x+bias). FIN: 0 plain store, 1 (+res then LayerNorm).
// grid (TOK/64, ncols/128); FIN=1 requires gridDim.y==1, 128-wide.
template<int ACT, int FIN>
__global__ __launch_bounds__(256) void gemm_mfma(
    const float* __restrict__ A, int lda, int K,
    const u16* __restrict__ BT, const float* __restrict__ bias,
    const float* __restrict__ res, float* __restrict__ out, int ldo)
{
  const int tid = threadIdx.x;
  const int t0 = blockIdx.x * 64;
  const int n0 = blockIdx.y * 128;
  __shared__ __align__(16) u16 As[64*40];
  __shared__ __align__(16) u16 Bs[128*40];
  const int wave = tid >> 6, lane = tid & 63, quad = lane >> 4, l15 = lane & 15;
  facc acc[8];
  #pragma unroll
  for (int g = 0; g < 8; ++g) acc[g] = (facc){0.f,0.f,0.f,0.f};
  const u16* BTn = BT + (size_t)n0*K;

  for (int k0 = 0; k0 < K; k0 += 32){
    { // stage A: 64x32 fp32 -> bf16
      const int row = tid >> 2, ko = tid & 3;
      const float* ap = A + (size_t)(t0+row)*lda + k0 + ko*8;
      float4 a0 = *(const float4*)ap, a1 = *(const float4*)(ap+4);
      uint4 u = { pk2(a0.x,a0.y), pk2(a0.z,a0.w), pk2(a1.x,a1.y), pk2(a1.z,a1.w) };
      *(uint4*)&As[row*40 + ko*8] = u;
    }
    { // stage B: 128x32 bf16 copy
      const int n = tid >> 1, part = tid & 1;
      const u16* wp = BTn + (size_t)n*K + k0 + part*16;
      uint4 w0 = *(const uint4*)wp, w1 = *(const uint4*)(wp+8);
      *(uint4*)&Bs[n*40 + part*16]     = w0;
      *(uint4*)&Bs[n*40 + part*16 + 8] = w1;
    }
    __syncthreads();
    bfrag af = *(const bfrag*)&As[(wave*16 + l15)*40 + quad*8];
    #pragma unroll
    for (int g = 0; g < 8; ++g){
      bfrag bf = *(const bfrag*)&Bs[(g*16 + l15)*40 + quad*8];
      acc[g] = __builtin_amdgcn_mfma_f32_16x16x32_bf16(af, bf, acc[g], 0,0,0);
    }
    __syncthreads();
  }

  float bv[8];
  #pragma unroll
  for (int g = 0; g < 8; ++g) bv[g] = bias[n0 + g*16 + l15];

  if (FIN == 0){
    #pragma unroll
    for (int g = 0; g < 8; ++g){
      const int c = n0 + g*16 + l15;
      #pragma unroll
      for (int q = 0; q < 4; ++q){
        const int rq = t0 + wave*16 + quad*4 + q;
        float xv = acc[g][q] + bv[g];
        if (ACT) xv = lrelu(xv);
        out[(size_t)rq*ldo + c] = xv;
      }
    }
  } else {
    float v[8][4];
    float s[4] = {0,0,0,0}, sq[4] = {0,0,0,0};
    #pragma unroll
    for (int q = 0; q < 4; ++q){
      const int rq = t0 + wave*16 + quad*4 + q;
      #pragma unroll
      for (int g = 0; g < 8; ++g){
        float xv = acc[g][q] + bv[g];
        if (ACT) xv = lrelu(xv);
        xv += res[(size_t)rq*128 + g*16 + l15];
        v[g][q] = xv; s[q] += xv; sq[q] += xv*xv;
      }
    }
    #pragma unroll
    for (int m = 1; m < 16; m <<= 1){
      #pragma unroll
      for (int q = 0; q < 4; ++q){ s[q] += __shfl_xor(s[q], m, 64); sq[q] += __shfl_xor(sq[q], m, 64); }
    }
    #pragma unroll
    for (int q = 0; q < 4; ++q){
      const int rq = t0 + wave*16 + quad*4 + q;
      const float mean = s[q]*(1.f/D);
      const float rstd = rsqrtf(sq[q]*(1.f/D) - mean*mean + 1e-5f);
      #pragma unroll
      for (int g = 0; g < 8; ++g)
        out[(size_t)rq*128 + g*16 + l15] = (v[g][q] - mean)*rstd;
    }
  }
}

// ---------------- Wh = h @ W[head], fused s1/s2, transposed bf16 store --------
// grid = nheads*64. WhT layout: [h][b][o=128][j=512] bf16.
__global__ __launch_bounds__(256) void wh_mfma(
    const float* __restrict__ hin, const u16* __restrict__ WT,
    const float* __restrict__ a, u16* __restrict__ WhT,
    float* __restrict__ s1, float* __restrict__ s2)
{
  const int tid = threadIdx.x;
  const int h  = blockIdx.x >> 6;
  const int t0 = (blockIdx.x & 63) * 64;
  const int b = t0 >> 9, j0 = t0 & (N-1);
  __shared__ __align__(16) u16 As[64*40];
  __shared__ __align__(16) u16 Bs[128*40];
  const int wave = tid >> 6, lane = tid & 63, quad = lane >> 4, l15 = lane & 15;
  facc acc[8];
  #pragma unroll
  for (int g = 0; g < 8; ++g) acc[g] = (facc){0.f,0.f,0.f,0.f};
  const u16* BTn = WT + (size_t)h*D*D;

  for (int k0 = 0; k0 < D; k0 += 32){
    { const int row = tid >> 2, ko = tid & 3;
      const float* ap = hin + (size_t)(t0+row)*D + k0 + ko*8;
      float4 a0 = *(const float4*)ap, a1 = *(const float4*)(ap+4);
      uint4 u = { pk2(a0.x,a0.y), pk2(a0.z,a0.w), pk2(a1.x,a1.y), pk2(a1.z,a1.w) };
      *(uint4*)&As[row*40 + ko*8] = u;
    }
    { const int n = tid >> 1, part = tid & 1;
      const u16* wp = BTn + (size_t)n*D + k0 + part*16;
      uint4 w0 = *(const uint4*)wp, w1 = *(const uint4*)(wp+8);
      *(uint4*)&Bs[n*40 + part*16]     = w0;
      *(uint4*)&Bs[n*40 + part*16 + 8] = w1;
    }
    __syncthreads();
    bfrag af = *(const bfrag*)&As[(wave*16 + l15)*40 + quad*8];
    #pragma unroll
    for (int g = 0; g < 8; ++g){
      bfrag bf = *(const bfrag*)&Bs[(g*16 + l15)*40 + quad*8];
      acc[g] = __builtin_amdgcn_mfma_f32_16x16x32_bf16(af, bf, acc[g], 0,0,0);
    }
    __syncthreads();
  }

  const float* ah = a + (size_t)h*2*D;
  const size_t obase = (size_t)(h*8 + b)*128;
  float p1[4] = {0,0,0,0}, p2[4] = {0,0,0,0};
  #pragma unroll
  for (int g = 0; g < 8; ++g){
    const int c = g*16 + l15;
    const float a1v = ah[c], a2v = ah[D + c];
    ushort4 wv;
    wv.x = f2bf(acc[g][0]); wv.y = f2bf(acc[g][1]);
    wv.z = f2bf(acc[g][2]); wv.w = f2bf(acc[g][3]);
    *(ushort4*)&WhT[(obase + c)*N + j0 + wave*16 + quad*4] = wv;
    #pragma unroll
    for (int q = 0; q < 4; ++q){
      p1[q] = fmaf(acc[g][q], a1v, p1[q]);
      p2[q] = fmaf(acc[g][q], a2v, p2[q]);
    }
  }
  #pragma unroll
  for (int m = 1; m < 16; m <<= 1){
    #pragma unroll
    for (int q = 0; q < 4; ++q){ p1[q] += __shfl_xor(p1[q], m, 64); p2[q] += __shfl_xor(p2[q], m, 64); }
  }
  if (l15 == 0){
    #pragma unroll
    for (int q = 0; q < 4; ++q){
      const int idx = h*TOK + t0 + wave*16 + quad*4 + q;
      s1[idx] = p1[q]; s2[idx] = p2[q];
    }
  }
}

// ---------------- fused score+softmax+PV (MFMA) -------------------------------
// MODE 0: elu, MODE 1: lrelu. grid = nheads*64.
template<int MODE>
__global__ __launch_bounds__(256) void pv_mfma(
    const float* __restrict__ s1, const float* __restrict__ s2,
    const int* __restrict__ mask, const u16* __restrict__ WhT,
    float* __restrict__ out, int ldo, int hcs)
{
  const int tid = threadIdx.x;
  const int h  = blockIdx.x >> 6;
  const int t0 = (blockIdx.x & 63) * 64;
  const int b = t0 >> 9, i0 = t0 & (N-1);
  __shared__ float s2s[N];
  __shared__ float s1s[64], mxs[64], invs[64];
  __shared__ __align__(16) u16 As[64*40];
  __shared__ __align__(16) u16 Bs[128*40];

  s2s[tid]     = s2[(size_t)h*TOK + b*N + tid];
  s2s[tid+256] = s2[(size_t)h*TOK + b*N + tid + 256];
  if (tid < 64) s1s[tid] = s1[(size_t)h*TOK + b*N + i0 + tid];
  __syncthreads();

  { // per-row softmax stats: 4 threads/row x 128 cols (fp32, verified R2)
    const int row = tid >> 2, q = tid & 3;
    const float s1v = s1s[row];
    const int4* mp = (const int4*)(mask + ((size_t)b*N + i0 + row)*N + q*128);
    float mx = -3.4e38f;
    #pragma unroll 8
    for (int it = 0; it < 32; ++it){
      int4 m4 = mp[it];
      int jb = q*128 + it*4;
      float e0 = lrelu(s1v*s2s[jb+0]), e1 = lrelu(s1v*s2s[jb+1]);
      float e2 = lrelu(s1v*s2s[jb+2]), e3 = lrelu(s1v*s2s[jb+3]);
      mx = fmaxf(mx, m4.x>0 ? e0 : -3.4e38f);
      mx = fmaxf(mx, m4.y>0 ? e1 : -3.4e38f);
      mx = fmaxf(mx, m4.z>0 ? e2 : -3.4e38f);
      mx = fmaxf(mx, m4.w>0 ? e3 : -3.4e38f);
    }
    #pragma unroll
    for (int m = 1; m < 4; m <<= 1) mx = fmaxf(mx, __shfl_xor(mx, m, 64));
    float sum = 0.f;
    #pragma unroll 8
    for (int it = 0; it < 32; ++it){
      int4 m4 = mp[it];
      int jb = q*128 + it*4;
      float e0 = lrelu(s1v*s2s[jb+0]), e1 = lrelu(s1v*s2s[jb+1]);
      float e2 = lrelu(s1v*s2s[jb+2]), e3 = lrelu(s1v*s2s[jb+3]);
      sum += m4.x>0 ? __expf(e0-mx) : 0.f;
      sum += m4.y>0 ? __expf(e1-mx) : 0.f;
      sum += m4.z>0 ? __expf(e2-mx) : 0.f;
      sum += m4.w>0 ? __expf(e3-mx) : 0.f;
    }
    #pragma unroll
    for (int m = 1; m < 4; m <<= 1) sum += __shfl_xor(sum, m, 64);
    if (q == 0){ mxs[row] = mx; invs[row] = (sum > 0.f) ? 1.f/sum : 0.f; }
  }
  __syncthreads();

  const u16* BTn = WhT + (size_t)(h*8 + b)*128*N;   // [o=128][j=512] bf16
  const int wave = tid >> 6, lane = tid & 63, quad = lane >> 4, l15 = lane & 15;
  facc acc[8];
  #pragma unroll
  for (int g = 0; g < 8; ++g) acc[g] = (facc){0.f,0.f,0.f,0.f};

  const int lr = tid >> 2, lq = tid & 3;
  const float s1lr = s1s[lr], mxlr = mxs[lr], invlr = invs[lr];
  const int* mrow = mask + ((size_t)b*N + i0 + lr)*N;

  for (int k0 = 0; k0 < N; k0 += 32){
    { // regenerate att chunk in bf16: row lr, k = k0+lq*8 ..+7
      const int4* mp = (const int4*)(mrow + k0 + lq*8);
      int4 m0 = mp[0], m1 = mp[1];
      const int jb = k0 + lq*8;
      int mm[8] = {m0.x,m0.y,m0.z,m0.w,m1.x,m1.y,m1.z,m1.w};
      float v[8];
      #pragma unroll
      for (int w2 = 0; w2 < 8; ++w2){
        float e = lrelu(s1lr * s2s[jb+w2]);
        v[w2] = (mm[w2] > 0) ? __expf(e - mxlr)*invlr : 0.f;
      }
      uint4 u = { pk2(v[0],v[1]), pk2(v[2],v[3]), pk2(v[4],v[5]), pk2(v[6],v[7]) };
      *(uint4*)&As[lr*40 + lq*8] = u;
    }
    { const int n = tid >> 1, part = tid & 1;
      const u16* wp = BTn + (size_t)n*N + k0 + part*16;
      uint4 w0 = *(const uint4*)wp, w1 = *(const uint4*)(wp+8);
      *(uint4*)&Bs[n*40 + part*16]     = w0;
      *(uint4*)&Bs[n*40 + part*16 + 8] = w1;
    }
    __syncthreads();
    bfrag af = *(const bfrag*)&As[(wave*16 + l15)*40 + quad*8];
    #pragma unroll
    for (int g = 0; g < 8; ++g){
      bfrag bf = *(const bfrag*)&Bs[(g*16 + l15)*40 + quad*8];
      acc[g] = __builtin_amdgcn_mfma_f32_16x16x32_bf16(af, bf, acc[g], 0,0,0);
    }
    __syncthreads();
  }

  #pragma unroll
  for (int g = 0; g < 8; ++g){
    const int c = h*hcs + g*16 + l15;
    #pragma unroll
    for (int q = 0; q < 4; ++q){
      const int rq = t0 + wave*16 + quad*4 + q;
      float xv = acc[g][q];
      xv = (MODE == 0) ? (xv > 0.f ? xv : expm1f(xv)) : lrelu(xv);
      out[(size_t)rq*ldo + c] = xv;
    }
  }
}

// ---------------- mean over n + projection -----------------------------------
__global__ void final_kernel(const float* __restrict__ hF, const float* __restrict__ hT,
                             const float* __restrict__ pW, const float* __restrict__ pb,
                             float* __restrict__ out)
{
  const int b = blockIdx.x, c = threadIdx.x;
  __shared__ float scr[4];
  const float* src = (c < D) ? (hF + (size_t)b*N*D + c) : (hT + (size_t)b*N*D + (c - D));
  float s = 0.f;
  for (int n = 0; n < N; ++n) s += src[(size_t)n*D];
  s *= (1.f/N);
  float p = s * pW[c];
  #pragma unroll
  for (int m = 32; m; m >>= 1) p += __shfl_xor(p, m, 64);
  __syncthreads();
  if ((c & 63) == 0) scr[c >> 6] = p;
  __syncthreads();
  if (c == 0) out[b] = scr[0] + scr[1] + scr[2] + scr[3] + pb[0];
}

extern "C" void kernel_launch(void* const* d_in, const int* in_sizes, int n_in,
                              void* d_out, int out_size, void* d_ws, size_t ws_size,
                              hipStream_t stream)
{
  (void)in_sizes; (void)n_in; (void)out_size; (void)ws_size;
  const float* x    = (const float*)d_in[0];
  const int*   adj  = (const int*)d_in[1];
  const float* f1w1 = (const float*)d_in[3];
  const float* f1b1 = (const float*)d_in[4];
  const float* f1w2 = (const float*)d_in[5];
  const float* f1b2 = (const float*)d_in[6];
  const float* f2w1 = (const float*)d_in[7];
  const float* f2b1 = (const float*)d_in[8];
  const float* f2w2 = (const float*)d_in[9];
  const float* f2b2 = (const float*)d_in[10];
  const float* f3w1 = (const float*)d_in[11];
  const float* f3b1 = (const float*)d_in[12];
  const float* f3w2 = (const float*)d_in[13];
  const float* f3b2 = (const float*)d_in[14];
  const float* attW = (const float*)d_in[15];
  const float* attA = (const float*)d_in[16];
  const float* rshW = (const float*)d_in[17];
  const float* rshB = (const float*)d_in[18];
  const float* outW = (const float*)d_in[19];
  const float* outA = (const float*)d_in[20];
  const float* pW   = (const float*)d_in[21];
  const float* pb   = (const float*)d_in[22];

  char* w = (char*)d_ws;
  float* hA  = (float*)w; w += (size_t)TOK*128*4;
  float* hB  = (float*)w; w += (size_t)TOK*128*4;
  float* hF  = (float*)w; w += (size_t)TOK*128*4;
  float* hp2 = (float*)w; w += (size_t)TOK*512*4;
  u16*  WhT  = (u16*)w;  w += (size_t)H*8*128*N*2;
  float* s1  = (float*)w; w += (size_t)H*TOK*4;
  float* s2  = (float*)w; w += (size_t)H*TOK*4;
  int* adjT  = (int*)w;  w += (size_t)B*N*N*4;
  u16* f1w1T = (u16*)w; w += 128*32*2;
  u16* f1w2T = (u16*)w; w += 128*128*2;
  u16* f2w1T = (u16*)w; w += 256*128*2;
  u16* f2w2T = (u16*)w; w += 128*256*2;
  u16* f3w1T = (u16*)w; w += 256*128*2;
  u16* f3w2T = (u16*)w; w += 128*256*2;
  u16* attWT = (u16*)w; w += (size_t)24*128*128*2;
  u16* outWT = (u16*)w; w += (size_t)2*128*128*2;
  u16* rshWT = (u16*)w; w += (size_t)6*128*512*2;

  // ---- weight transposes (fp32 -> bf16, [n][k]) ----
  wtrans<<<dim3(4,1,1),  256,0,stream>>>(f1w1, f1w1T, 32, 128);
  wtrans<<<dim3(4,4,1),  256,0,stream>>>(f1w2, f1w2T, 128,128);
  wtrans<<<dim3(8,4,1),  256,0,stream>>>(f2w1, f2w1T, 128,256);
  wtrans<<<dim3(4,8,1),  256,0,stream>>>(f2w2, f2w2T, 256,128);
  wtrans<<<dim3(8,4,1),  256,0,stream>>>(f3w1, f3w1T, 128,256);
  wtrans<<<dim3(4,8,1),  256,0,stream>>>(f3w2, f3w2T, 256,128);
  wtrans<<<dim3(4,4,24), 256,0,stream>>>(attW, attWT, 128,128);
  wtrans<<<dim3(4,4,2),  256,0,stream>>>(outW, outWT, 128,128);
  wtrans<<<dim3(4,16,6), 256,0,stream>>>(rshW, rshWT, 512,128);
  transpose_kernel<<<dim3(16,16,8),256,0,stream>>>(adj, adjT);

  // ---- FEL as 6 fused MFMA GEMM stages ----
  gemm_mfma<1,0><<<dim3(64,1),256,0,stream>>>(x,   32, 32,  f1w1T, f1b1, nullptr, hF, 128);
  gemm_mfma<1,0><<<dim3(64,1),256,0,stream>>>(hF, 128, 128, f1w2T, f1b2, nullptr, hB, 128);
  gemm_mfma<1,0><<<dim3(64,2),256,0,stream>>>(hB, 128, 128, f2w1T, f2b1, nullptr, hp2, 256);
  gemm_mfma<1,1><<<dim3(64,1),256,0,stream>>>(hp2,256, 256, f2w2T, f2b2, hB, hF, 128);
  gemm_mfma<1,0><<<dim3(64,2),256,0,stream>>>(hF, 128, 128, f3w1T, f3b1, nullptr, hp2, 256);
  gemm_mfma<0,1><<<dim3(64,1),256,0,stream>>>(hp2,256, 256, f3w2T, f3b2, hF, hA, 128);

  // ---- forward attention blocks 0..2 ----
  float* cur = hA; float* nxt = hB;
  for (int i = 0; i < 3; ++i){
    wh_mfma<<<H*64,256,0,stream>>>(cur, attWT + (size_t)i*H*D*D,
                                   attA + (size_t)i*H*2*D, WhT, s1, s2);
    pv_mfma<0><<<H*64,256,0,stream>>>(s1, s2, adj, WhT, hp2, 512, 128);
    gemm_mfma<0,1><<<dim3(64,1),256,0,stream>>>(hp2, 512, 512,
        rshWT + (size_t)i*128*512, rshB + (size_t)i*D, cur, nxt, 128);
    float* t_ = cur; cur = nxt; nxt = t_;
  }
  // forward output GAT (single head, lrelu) -> hF
  wh_mfma<<<64,256,0,stream>>>(cur, outWT, outA, WhT, s1, s2);
  pv_mfma<1><<<64,256,0,stream>>>(s1, s2, adj, WhT, hF, 128, 0);

  // ---- transposed attention blocks 3..5 ----
  cur = hF; nxt = hA;
  for (int i = 3; i < 6; ++i){
    wh_mfma<<<H*64,256,0,stream>>>(cur, attWT + (size_t)i*H*D*D,
                                   attA + (size_t)i*H*2*D, WhT, s1, s2);
    pv_mfma<0><<<H*64,256,0,stream>>>(s1, s2, adjT, WhT, hp2, 512, 128);
    gemm_mfma<0,1><<<dim3(64,1),256,0,stream>>>(hp2, 512, 512,
        rshWT + (size_t)i*128*512, rshB + (size_t)i*D, cur, nxt, 128);
    cur = nxt; nxt = (cur == hA) ? hB : hA;
  }
  // transposed output GAT -> nxt (hA or hB, distinct from hF and cur)
  wh_mfma<<<64,256,0,stream>>>(cur, outWT + 128*128, outA + 2*D, WhT, s1, s2);
  pv_mfma<1><<<64,256,0,stream>>>(s1, s2, adjT, WhT, nxt, 128, 0);

  final_kernel<<<B,2*D,0,stream>>>(hF, nxt, pW, pb, (float*)d_out);
}

// Round 4
// 499.606 us; speedup vs baseline: 3.6922x; 1.0810x over previous
//
#include <hip/hip_runtime.h>
#include <math.h>

#define B 8
#define N 512
#define D 128
#define H 4
#define TOK (B*N)   // 4096

typedef __attribute__((ext_vector_type(8))) short bfrag;   // 8 bf16 (4 VGPRs)
typedef __attribute__((ext_vector_type(4))) float facc;    // 4 fp32 acc
typedef unsigned short u16;
typedef unsigned int u32;

__device__ __forceinline__ float lrelu(float x){ return x > 0.f ? x : 0.01f*x; }
__device__ __forceinline__ u16 f2bf(float f){
  u32 u = __float_as_uint(f);
  u += 0x7fffu + ((u >> 16) & 1u);     // RTNE
  return (u16)(u >> 16);
}
__device__ __forceinline__ u32 pk2(float a, float b){
  return (u32)f2bf(a) | ((u32)f2bf(b) << 16);
}

// ---------------- unified prep: adj transpose + all weight bf16-transposes ----
// grid 512: blocks 0..127 adjT (8 batches x 16 row-panels), 128..511 weight tiles
__global__ void prep_kernel(const int* __restrict__ adj, int* __restrict__ adjT,
    const float* s0, const float* s1_, const float* s2_, const float* s3,
    const float* s4, const float* s5, const float* s6, const float* s7,
    const float* s8,
    u16* d0, u16* d1, u16* d2, u16* d3, u16* d4, u16* d5, u16* d6, u16* d7, u16* d8)
{
  __shared__ float ftile[32][33];
  const int tid = threadIdx.x;
  const int tx = tid & 31, ty = tid >> 5;
  if (blockIdx.x < 128){
    int* it = (int*)&ftile[0][0];
    const int b = blockIdx.x >> 4, i0 = (blockIdx.x & 15)*32;
    for (int j0 = 0; j0 < N; j0 += 32){
      for (int r = ty; r < 32; r += 8)
        it[r*33 + tx] = adj[((size_t)b*N + i0 + r)*N + j0 + tx];
      __syncthreads();
      for (int r = ty; r < 32; r += 8)
        adjT[((size_t)b*N + j0 + r)*N + i0 + tx] = it[tx*33 + r];
      __syncthreads();
    }
  } else {
    const float* srcs[9] = {s0,s1_,s2_,s3,s4,s5,s6,s7,s8};
    u16* dsts[9] = {d0,d1,d2,d3,d4,d5,d6,d7,d8};
    const int Ks[9] = {32,128,128,256,128,256,128,128,512};
    const int Ns[9] = {128,128,256,128,256,128,128,128,128};
    const int zs[9] = {1,1,1,1,1,1,24,2,6};
    for (int job = (int)blockIdx.x - 128; job < 948; job += 384){
      int m = 0, base = 0;
      for (; m < 9; ++m){
        int cnt = (Ks[m]>>5)*(Ns[m]>>5)*zs[m];
        if (job < base + cnt) break;
        base += cnt;
      }
      const int rem = job - base;
      const int tn = Ns[m] >> 5;
      const int per = (Ks[m] >> 5)*tn;
      const int z = rem / per, t = rem % per;
      const int k0 = (t / tn)*32, n0 = (t % tn)*32;
      const float* src = srcs[m] + (size_t)z*Ks[m]*Ns[m];
      u16* dst = dsts[m] + (size_t)z*Ks[m]*Ns[m];
      __syncthreads();
      for (int r = ty; r < 32; r += 8)
        ftile[r][tx] = src[(size_t)(k0+r)*Ns[m] + n0 + tx];
      __syncthreads();
      for (int r = ty; r < 32; r += 8)
        dst[(size_t)(n0+r)*Ks[m] + k0 + tx] = f2bf(ftile[tx][r]);
    }
  }
}

// ---------------- generic 64x128 GEMM + epilogue (FEL stages + resh) ----------
// ACT: 0 none, 1 lrelu(x+bias). FIN: 0 plain store, 1 (+res then LayerNorm).
template<int ACT, int FIN>
__global__ __launch_bounds__(256) void gemm_mfma(
    const float* __restrict__ A, int lda, int K,
    const u16* __restrict__ BT, const float* __restrict__ bias,
    const float* __restrict__ res, float* __restrict__ out, int ldo)
{
  const int tid = threadIdx.x;
  const int t0 = blockIdx.x * 64;
  const int n0 = blockIdx.y * 128;
  __shared__ __align__(16) u16 As[64*40];
  __shared__ __align__(16) u16 Bs[128*40];
  const int wave = tid >> 6, lane = tid & 63, quad = lane >> 4, l15 = lane & 15;
  facc acc[8];
  #pragma unroll
  for (int g = 0; g < 8; ++g) acc[g] = (facc){0.f,0.f,0.f,0.f};
  const u16* BTn = BT + (size_t)n0*K;

  for (int k0 = 0; k0 < K; k0 += 32){
    { const int row = tid >> 2, ko = tid & 3;
      const float* ap = A + (size_t)(t0+row)*lda + k0 + ko*8;
      float4 a0 = *(const float4*)ap, a1 = *(const float4*)(ap+4);
      uint4 u = { pk2(a0.x,a0.y), pk2(a0.z,a0.w), pk2(a1.x,a1.y), pk2(a1.z,a1.w) };
      *(uint4*)&As[row*40 + ko*8] = u;
    }
    { const int n = tid >> 1, part = tid & 1;
      const u16* wp = BTn + (size_t)n*K + k0 + part*16;
      uint4 w0 = *(const uint4*)wp, w1 = *(const uint4*)(wp+8);
      *(uint4*)&Bs[n*40 + part*16]     = w0;
      *(uint4*)&Bs[n*40 + part*16 + 8] = w1;
    }
    __syncthreads();
    bfrag af = *(const bfrag*)&As[(wave*16 + l15)*40 + quad*8];
    #pragma unroll
    for (int g = 0; g < 8; ++g){
      bfrag bf = *(const bfrag*)&Bs[(g*16 + l15)*40 + quad*8];
      acc[g] = __builtin_amdgcn_mfma_f32_16x16x32_bf16(af, bf, acc[g], 0,0,0);
    }
    __syncthreads();
  }

  float bv[8];
  #pragma unroll
  for (int g = 0; g < 8; ++g) bv[g] = bias[n0 + g*16 + l15];

  if (FIN == 0){
    #pragma unroll
    for (int g = 0; g < 8; ++g){
      const int c = n0 + g*16 + l15;
      #pragma unroll
      for (int q = 0; q < 4; ++q){
        const int rq = t0 + wave*16 + quad*4 + q;
        float xv = acc[g][q] + bv[g];
        if (ACT) xv = lrelu(xv);
        out[(size_t)rq*ldo + c] = xv;
      }
    }
  } else {
    float v[8][4];
    float s[4] = {0,0,0,0}, sq[4] = {0,0,0,0};
    #pragma unroll
    for (int q = 0; q < 4; ++q){
      const int rq = t0 + wave*16 + quad*4 + q;
      #pragma unroll
      for (int g = 0; g < 8; ++g){
        float xv = acc[g][q] + bv[g];
        if (ACT) xv = lrelu(xv);
        xv += res[(size_t)rq*128 + g*16 + l15];
        v[g][q] = xv; s[q] += xv; sq[q] += xv*xv;
      }
    }
    #pragma unroll
    for (int m = 1; m < 16; m <<= 1){
      #pragma unroll
      for (int q = 0; q < 4; ++q){ s[q] += __shfl_xor(s[q], m, 64); sq[q] += __shfl_xor(sq[q], m, 64); }
    }
    #pragma unroll
    for (int q = 0; q < 4; ++q){
      const int rq = t0 + wave*16 + quad*4 + q;
      const float mean = s[q]*(1.f/D);
      const float rstd = rsqrtf(sq[q]*(1.f/D) - mean*mean + 1e-5f);
      #pragma unroll
      for (int g = 0; g < 8; ++g)
        out[(size_t)rq*128 + g*16 + l15] = (v[g][q] - mean)*rstd;
    }
  }
}

// ---------------- Wh (32x128 tiles, 2 blocks/CU) + fused s1/s2 ---------------
// grid = nheads*128. Wave w: rows (w&1)*16.., cols (w>>1)*64.. (4 frags).
__global__ __launch_bounds__(256) void wh32(
    const float* __restrict__ hin, const u16* __restrict__ WT,
    const float* __restrict__ a, u16* __restrict__ WhT,
    float* __restrict__ s1, float* __restrict__ s2)
{
  const int tid = threadIdx.x;
  const int h  = blockIdx.x >> 7;
  const int t0 = (blockIdx.x & 127) * 32;
  const int b = t0 >> 9, j0 = t0 & (N-1);
  __shared__ __align__(16) u16 As[32*40];
  __shared__ __align__(16) u16 Bs[128*40];
  __shared__ float r1s[2][32], r2s[2][32];
  const int wave = tid >> 6, lane = tid & 63, quad = lane >> 4, l15 = lane & 15;
  const int r0 = (wave & 1)*16, c0 = (wave >> 1)*64;
  facc acc[4];
  #pragma unroll
  for (int g = 0; g < 4; ++g) acc[g] = (facc){0.f,0.f,0.f,0.f};
  const u16* BTn = WT + (size_t)h*D*D;

  for (int k0 = 0; k0 < D; k0 += 32){
    { const int row = tid >> 3, ko = tid & 7;
      float4 a0 = *(const float4*)(hin + (size_t)(t0+row)*D + k0 + ko*4);
      uint2 u = { pk2(a0.x,a0.y), pk2(a0.z,a0.w) };
      *(uint2*)&As[row*40 + ko*4] = u;
    }
    { const int n = tid >> 1, part = tid & 1;
      const u16* wp = BTn + (size_t)n*D + k0 + part*16;
      uint4 w0 = *(const uint4*)wp, w1 = *(const uint4*)(wp+8);
      *(uint4*)&Bs[n*40 + part*16]     = w0;
      *(uint4*)&Bs[n*40 + part*16 + 8] = w1;
    }
    __syncthreads();
    bfrag af = *(const bfrag*)&As[(r0 + l15)*40 + quad*8];
    #pragma unroll
    for (int g = 0; g < 4; ++g){
      bfrag bf = *(const bfrag*)&Bs[(c0 + g*16 + l15)*40 + quad*8];
      acc[g] = __builtin_amdgcn_mfma_f32_16x16x32_bf16(af, bf, acc[g], 0,0,0);
    }
    __syncthreads();
  }

  const float* ah = a + (size_t)h*2*D;
  const size_t obase = (size_t)(h*8 + b)*128;
  float p1[4] = {0,0,0,0}, p2[4] = {0,0,0,0};
  #pragma unroll
  for (int g = 0; g < 4; ++g){
    const int c = c0 + g*16 + l15;
    const float a1v = ah[c], a2v = ah[D + c];
    ushort4 wv;
    wv.x = f2bf(acc[g][0]); wv.y = f2bf(acc[g][1]);
    wv.z = f2bf(acc[g][2]); wv.w = f2bf(acc[g][3]);
    *(ushort4*)&WhT[(obase + c)*N + j0 + r0 + quad*4] = wv;
    #pragma unroll
    for (int q = 0; q < 4; ++q){
      p1[q] = fmaf(acc[g][q], a1v, p1[q]);
      p2[q] = fmaf(acc[g][q], a2v, p2[q]);
    }
  }
  #pragma unroll
  for (int m = 1; m < 16; m <<= 1){
    #pragma unroll
    for (int q = 0; q < 4; ++q){ p1[q] += __shfl_xor(p1[q], m, 64); p2[q] += __shfl_xor(p2[q], m, 64); }
  }
  if (l15 == 0){
    #pragma unroll
    for (int q = 0; q < 4; ++q){
      r1s[wave>>1][r0 + quad*4 + q] = p1[q];
      r2s[wave>>1][r0 + quad*4 + q] = p2[q];
    }
  }
  __syncthreads();
  if (tid < 32){
    s1[(size_t)h*TOK + t0 + tid] = r1s[0][tid] + r1s[1][tid];
    s2[(size_t)h*TOK + t0 + tid] = r2s[0][tid] + r2s[1][tid];
  }
}

// ---------------- fused score+softmax+PV (32x128 tiles) -----------------------
// MODE 0: elu, MODE 1: lrelu. grid = nheads*128.
template<int MODE>
__global__ __launch_bounds__(256) void pv32(
    const float* __restrict__ s1, const float* __restrict__ s2,
    const int* __restrict__ mask, const u16* __restrict__ WhT,
    float* __restrict__ out, int ldo, int hcs)
{
  const int tid = threadIdx.x;
  const int h  = blockIdx.x >> 7;
  const int t0 = (blockIdx.x & 127) * 32;
  const int b = t0 >> 9, i0 = t0 & (N-1);
  __shared__ float s2s[N];
  __shared__ float s1s[32], mxs[32], invs[32];
  __shared__ __align__(16) u16 As[32*40];
  __shared__ __align__(16) u16 Bs[128*40];

  s2s[tid]     = s2[(size_t)h*TOK + b*N + tid];
  s2s[tid+256] = s2[(size_t)h*TOK + b*N + tid + 256];
  if (tid < 32) s1s[tid] = s1[(size_t)h*TOK + t0 + tid];
  __syncthreads();

  { // per-row stats: 8 threads/row x 64 cols
    const int row = tid >> 3, q = tid & 7;
    const float s1v = s1s[row];
    const int4* mp = (const int4*)(mask + ((size_t)b*N + i0 + row)*N + q*64);
    float mx = -3.4e38f;
    #pragma unroll 4
    for (int it = 0; it < 16; ++it){
      int4 m4 = mp[it];
      int jb = q*64 + it*4;
      float e0 = lrelu(s1v*s2s[jb+0]), e1 = lrelu(s1v*s2s[jb+1]);
      float e2 = lrelu(s1v*s2s[jb+2]), e3 = lrelu(s1v*s2s[jb+3]);
      mx = fmaxf(mx, m4.x>0 ? e0 : -3.4e38f);
      mx = fmaxf(mx, m4.y>0 ? e1 : -3.4e38f);
      mx = fmaxf(mx, m4.z>0 ? e2 : -3.4e38f);
      mx = fmaxf(mx, m4.w>0 ? e3 : -3.4e38f);
    }
    #pragma unroll
    for (int m = 1; m < 8; m <<= 1) mx = fmaxf(mx, __shfl_xor(mx, m, 64));
    float sum = 0.f;
    #pragma unroll 4
    for (int it = 0; it < 16; ++it){
      int4 m4 = mp[it];
      int jb = q*64 + it*4;
      float e0 = lrelu(s1v*s2s[jb+0]), e1 = lrelu(s1v*s2s[jb+1]);
      float e2 = lrelu(s1v*s2s[jb+2]), e3 = lrelu(s1v*s2s[jb+3]);
      sum += m4.x>0 ? __expf(e0-mx) : 0.f;
      sum += m4.y>0 ? __expf(e1-mx) : 0.f;
      sum += m4.z>0 ? __expf(e2-mx) : 0.f;
      sum += m4.w>0 ? __expf(e3-mx) : 0.f;
    }
    #pragma unroll
    for (int m = 1; m < 8; m <<= 1) sum += __shfl_xor(sum, m, 64);
    if (q == 0){ mxs[row] = mx; invs[row] = (sum > 0.f) ? 1.f/sum : 0.f; }
  }
  __syncthreads();

  const u16* BTn = WhT + (size_t)(h*8 + b)*128*N;   // [o=128][j=512] bf16
  const int wave = tid >> 6, lane = tid & 63, quad = lane >> 4, l15 = lane & 15;
  const int r0 = (wave & 1)*16, c0 = (wave >> 1)*64;
  facc acc[4];
  #pragma unroll
  for (int g = 0; g < 4; ++g) acc[g] = (facc){0.f,0.f,0.f,0.f};

  const int lr = tid >> 3, lq = tid & 7;
  const float s1lr = s1s[lr], mxlr = mxs[lr], invlr = invs[lr];
  const int* mrow = mask + ((size_t)b*N + i0 + lr)*N;

  for (int k0 = 0; k0 < N; k0 += 32){
    { int4 m4 = *(const int4*)(mrow + k0 + lq*4);
      const int jb = k0 + lq*4;
      int mm[4] = {m4.x,m4.y,m4.z,m4.w};
      float v[4];
      #pragma unroll
      for (int w2 = 0; w2 < 4; ++w2){
        float e = lrelu(s1lr * s2s[jb+w2]);
        v[w2] = (mm[w2] > 0) ? __expf(e - mxlr)*invlr : 0.f;
      }
      uint2 u = { pk2(v[0],v[1]), pk2(v[2],v[3]) };
      *(uint2*)&As[lr*40 + lq*4] = u;
    }
    { const int n = tid >> 1, part = tid & 1;
      const u16* wp = BTn + (size_t)n*N + k0 + part*16;
      uint4 w0 = *(const uint4*)wp, w1 = *(const uint4*)(wp+8);
      *(uint4*)&Bs[n*40 + part*16]     = w0;
      *(uint4*)&Bs[n*40 + part*16 + 8] = w1;
    }
    __syncthreads();
    bfrag af = *(const bfrag*)&As[(r0 + l15)*40 + quad*8];
    #pragma unroll
    for (int g = 0; g < 4; ++g){
      bfrag bf = *(const bfrag*)&Bs[(c0 + g*16 + l15)*40 + quad*8];
      acc[g] = __builtin_amdgcn_mfma_f32_16x16x32_bf16(af, bf, acc[g], 0,0,0);
    }
    __syncthreads();
  }

  #pragma unroll
  for (int g = 0; g < 4; ++g){
    const int c = h*hcs + c0 + g*16 + l15;
    #pragma unroll
    for (int q = 0; q < 4; ++q){
      const int rq = t0 + r0 + quad*4 + q;
      float xv = acc[g][q];
      xv = (MODE == 0) ? (xv > 0.f ? xv : expm1f(xv)) : lrelu(xv);
      out[(size_t)rq*ldo + c] = xv;
    }
  }
}

// ---------------- mean over n + projection -----------------------------------
__global__ void final_kernel(const float* __restrict__ hF, const float* __restrict__ hT,
                             const float* __restrict__ pW, const float* __restrict__ pb,
                             float* __restrict__ out)
{
  const int b = blockIdx.x, c = threadIdx.x;
  __shared__ float scr[4];
  const float* src = (c < D) ? (hF + (size_t)b*N*D + c) : (hT + (size_t)b*N*D + (c - D));
  float s = 0.f;
  for (int n = 0; n < N; ++n) s += src[(size_t)n*D];
  s *= (1.f/N);
  float p = s * pW[c];
  #pragma unroll
  for (int m = 32; m; m >>= 1) p += __shfl_xor(p, m, 64);
  __syncthreads();
  if ((c & 63) == 0) scr[c >> 6] = p;
  __syncthreads();
  if (c == 0) out[b] = scr[0] + scr[1] + scr[2] + scr[3] + pb[0];
}

extern "C" void kernel_launch(void* const* d_in, const int* in_sizes, int n_in,
                              void* d_out, int out_size, void* d_ws, size_t ws_size,
                              hipStream_t stream)
{
  (void)in_sizes; (void)n_in; (void)out_size; (void)ws_size;
  const float* x    = (const float*)d_in[0];
  const int*   adj  = (const int*)d_in[1];
  const float* f1w1 = (const float*)d_in[3];
  const float* f1b1 = (const float*)d_in[4];
  const float* f1w2 = (const float*)d_in[5];
  const float* f1b2 = (const float*)d_in[6];
  const float* f2w1 = (const float*)d_in[7];
  const float* f2b1 = (const float*)d_in[8];
  const float* f2w2 = (const float*)d_in[9];
  const float* f2b2 = (const float*)d_in[10];
  const float* f3w1 = (const float*)d_in[11];
  const float* f3b1 = (const float*)d_in[12];
  const float* f3w2 = (const float*)d_in[13];
  const float* f3b2 = (const float*)d_in[14];
  const float* attW = (const float*)d_in[15];
  const float* attA = (const float*)d_in[16];
  const float* rshW = (const float*)d_in[17];
  const float* rshB = (const float*)d_in[18];
  const float* outW = (const float*)d_in[19];
  const float* outA = (const float*)d_in[20];
  const float* pW   = (const float*)d_in[21];
  const float* pb   = (const float*)d_in[22];

  char* w = (char*)d_ws;
  float* hA  = (float*)w; w += (size_t)TOK*128*4;
  float* hB  = (float*)w; w += (size_t)TOK*128*4;
  float* hF  = (float*)w; w += (size_t)TOK*128*4;
  float* hp2 = (float*)w; w += (size_t)TOK*512*4;
  u16*  WhT  = (u16*)w;  w += (size_t)H*8*128*N*2;
  float* s1  = (float*)w; w += (size_t)H*TOK*4;
  float* s2  = (float*)w; w += (size_t)H*TOK*4;
  int* adjT  = (int*)w;  w += (size_t)B*N*N*4;
  u16* f1w1T = (u16*)w; w += 128*32*2;
  u16* f1w2T = (u16*)w; w += 128*128*2;
  u16* f2w1T = (u16*)w; w += 256*128*2;
  u16* f2w2T = (u16*)w; w += 128*256*2;
  u16* f3w1T = (u16*)w; w += 256*128*2;
  u16* f3w2T = (u16*)w; w += 128*256*2;
  u16* attWT = (u16*)w; w += (size_t)24*128*128*2;
  u16* outWT = (u16*)w; w += (size_t)2*128*128*2;
  u16* rshWT = (u16*)w; w += (size_t)6*128*512*2;

  prep_kernel<<<512,256,0,stream>>>(adj, adjT,
      f1w1, f1w2, f2w1, f2w2, f3w1, f3w2, attW, outW, rshW,
      f1w1T, f1w2T, f2w1T, f2w2T, f3w1T, f3w2T, attWT, outWT, rshWT);

  // ---- FEL as 6 fused MFMA GEMM stages ----
  gemm_mfma<1,0><<<dim3(64,1),256,0,stream>>>(x,   32, 32,  f1w1T, f1b1, nullptr, hF, 128);
  gemm_mfma<1,0><<<dim3(64,1),256,0,stream>>>(hF, 128, 128, f1w2T, f1b2, nullptr, hB, 128);
  gemm_mfma<1,0><<<dim3(64,2),256,0,stream>>>(hB, 128, 128, f2w1T, f2b1, nullptr, hp2, 256);
  gemm_mfma<1,1><<<dim3(64,1),256,0,stream>>>(hp2,256, 256, f2w2T, f2b2, hB, hF, 128);
  gemm_mfma<1,0><<<dim3(64,2),256,0,stream>>>(hF, 128, 128, f3w1T, f3b1, nullptr, hp2, 256);
  gemm_mfma<0,1><<<dim3(64,1),256,0,stream>>>(hp2,256, 256, f3w2T, f3b2, hF, hA, 128);

  // ---- forward attention blocks 0..2 ----
  float* cur = hA; float* nxt = hB;
  for (int i = 0; i < 3; ++i){
    wh32<<<H*128,256,0,stream>>>(cur, attWT + (size_t)i*H*D*D,
                                 attA + (size_t)i*H*2*D, WhT, s1, s2);
    pv32<0><<<H*128,256,0,stream>>>(s1, s2, adj, WhT, hp2, 512, 128);
    gemm_mfma<0,1><<<dim3(64,1),256,0,stream>>>(hp2, 512, 512,
        rshWT + (size_t)i*128*512, rshB + (size_t)i*D, cur, nxt, 128);
    float* t_ = cur; cur = nxt; nxt = t_;
  }
  // forward output GAT (single head, lrelu) -> hF
  wh32<<<128,256,0,stream>>>(cur, outWT, outA, WhT, s1, s2);
  pv32<1><<<128,256,0,stream>>>(s1, s2, adj, WhT, hF, 128, 0);

  // ---- transposed attention blocks 3..5 ----
  cur = hF; nxt = hA;
  for (int i = 3; i < 6; ++i){
    wh32<<<H*128,256,0,stream>>>(cur, attWT + (size_t)i*H*D*D,
                                 attA + (size_t)i*H*2*D, WhT, s1, s2);
    pv32<0><<<H*128,256,0,stream>>>(s1, s2, adjT, WhT, hp2, 512, 128);
    gemm_mfma<0,1><<<dim3(64,1),256,0,stream>>>(hp2, 512, 512,
        rshWT + (size_t)i*128*512, rshB + (size_t)i*D, cur, nxt, 128);
    cur = nxt; nxt = (cur == hA) ? hB : hA;
  }
  // transposed output GAT -> nxt (hA or hB, distinct from hF and cur)
  wh32<<<128,256,0,stream>>>(cur, outWT + 128*128, outA + 2*D, WhT, s1, s2);
  pv32<1><<<128,256,0,stream>>>(s1, s2, adjT, WhT, nxt, 128, 0);

  final_kernel<<<B,2*D,0,stream>>>(hF, nxt, pW, pb, (float*)d_out);
}